// Round 3
// baseline (3449.965 us; speedup 1.0000x reference)
//
#include <hip/hip_runtime.h>
#include <hip/hip_fp16.h>

// N=512, C=3, T=300, V=25, M=2, F=150, H=100, gates=4H=400
// x element (n,c,t,v,m) at n*45000 + c*15000 + t*50 + (v*2+m)
// Weight-table column map: col t = 4*j + k  <->  gate-row k*100+j (k: 0=i,1=f,2=g,3=o)
// xg[n][tl][4*j+k] = gate k of cell j  (same map; produced by pre unchanged)

// ws layout (BYTE offsets):
#define B_W2P   0u          // uint[50][512]  dec folded Whh+Wih@fcW, f16-pair packed
#define B_WDP   102400u     // uint[50][512]  dec Whh (step-1)
#define B_WEP   204800u     // uint[50][512]  enc Whh
#define B_PIH   307200u     // uint[75][512]  enc Wih f16 pairs
#define B_BENC  460800u     // float[512]
#define B_B1    462848u     // float[512]
#define B_BEFF  464896u     // float[512]
#define B_HIST  466944u     // ushort hist[512][29952]
#define HIST_STRIDE 29952
#define B_XG    31137792u   // ushort xg[512][150][400]
// Phase-0 carry state parked at head of each sample's hist region:
//   h149 (f16) at histn[0..99]; c149 (f32) at byte offset 256 (histn+128 ushorts).
// Overwritten only by decoder steps 1..4 of the same phase-1 block, before emit.

typedef _Float16 h2_t __attribute__((ext_vector_type(2)));

#if defined(__has_builtin)
#if __has_builtin(__builtin_amdgcn_fdot2)
#define HAS_FDOT2 1
#endif
#endif

__device__ __forceinline__ float fdot2u(unsigned a, unsigned b, float c) {
#ifdef HAS_FDOT2
  return __builtin_amdgcn_fdot2(__builtin_bit_cast(h2_t, a), __builtin_bit_cast(h2_t, b), c, false);
#else
  float al = __half2float(__ushort_as_half((unsigned short)(a & 0xffffu)));
  float ah = __half2float(__ushort_as_half((unsigned short)(a >> 16)));
  float bl = __half2float(__ushort_as_half((unsigned short)(b & 0xffffu)));
  float bh = __half2float(__ushort_as_half((unsigned short)(b >> 16)));
  return fmaf(ah, bh, fmaf(al, bl, c));
#endif
}

__device__ __forceinline__ unsigned pack2f(float a, float b) {
  return (unsigned)__half_as_ushort(__float2half(a)) |
         ((unsigned)__half_as_ushort(__float2half(b)) << 16);
}

__device__ __forceinline__ float fast_sig(float x) {
  float e = __builtin_amdgcn_exp2f(x * -1.442695040888963f);
  return __builtin_amdgcn_rcpf(1.f + e);
}
__device__ __forceinline__ float fast_tanh(float x) {
  float e = __builtin_amdgcn_exp2f(x * -2.885390081777926f);
  return fmaf(2.f, __builtin_amdgcn_rcpf(1.f + e), -1.f);
}

// all-local LSTM cell update: a = (i,f,g,o) pre-activations
__device__ __forceinline__ float cell_update(float4 a, float& c) {
  float i = fast_sig(a.x), f = fast_sig(a.y);
  float g = fast_tanh(a.z), o = fast_sig(a.w);
  c = fmaf(f, c, i * g);
  return o * fast_tanh(c);
}

// 4-gate K=100 dot for one cell: 12 b128 + 1 b64 broadcast LDS reads, 200 fdot2
__device__ __forceinline__ float4 dot4(const unsigned short* hb, const uint4 (&wq)[50]) {
  float ai0 = 0.f, af0 = 0.f, ag0 = 0.f, ao0 = 0.f;
  float ai1 = 0.f, af1 = 0.f, ag1 = 0.f, ao1 = 0.f;
  const uint4* h4 = (const uint4*)hb;
#pragma unroll
  for (int ch = 0; ch < 12; ++ch) {
    uint4 hv = h4[ch];
    ai0 = fdot2u(wq[4 * ch + 0].x, hv.x, ai0);
    af0 = fdot2u(wq[4 * ch + 0].y, hv.x, af0);
    ag0 = fdot2u(wq[4 * ch + 0].z, hv.x, ag0);
    ao0 = fdot2u(wq[4 * ch + 0].w, hv.x, ao0);
    ai1 = fdot2u(wq[4 * ch + 1].x, hv.y, ai1);
    af1 = fdot2u(wq[4 * ch + 1].y, hv.y, af1);
    ag1 = fdot2u(wq[4 * ch + 1].z, hv.y, ag1);
    ao1 = fdot2u(wq[4 * ch + 1].w, hv.y, ao1);
    ai0 = fdot2u(wq[4 * ch + 2].x, hv.z, ai0);
    af0 = fdot2u(wq[4 * ch + 2].y, hv.z, af0);
    ag0 = fdot2u(wq[4 * ch + 2].z, hv.z, ag0);
    ao0 = fdot2u(wq[4 * ch + 2].w, hv.z, ao0);
    ai1 = fdot2u(wq[4 * ch + 3].x, hv.w, ai1);
    af1 = fdot2u(wq[4 * ch + 3].y, hv.w, af1);
    ag1 = fdot2u(wq[4 * ch + 3].z, hv.w, ag1);
    ao1 = fdot2u(wq[4 * ch + 3].w, hv.w, ao1);
  }
  uint2 hv2 = *(const uint2*)(hb + 96);
  ai0 = fdot2u(wq[48].x, hv2.x, ai0);
  af0 = fdot2u(wq[48].y, hv2.x, af0);
  ag0 = fdot2u(wq[48].z, hv2.x, ag0);
  ao0 = fdot2u(wq[48].w, hv2.x, ao0);
  ai1 = fdot2u(wq[49].x, hv2.y, ai1);
  af1 = fdot2u(wq[49].y, hv2.y, af1);
  ag1 = fdot2u(wq[49].z, hv2.y, ag1);
  ao1 = fdot2u(wq[49].w, hv2.y, ao1);
  return make_float4(ai0 + ai1, af0 + af1, ag0 + ag1, ao0 + ao1);
}

__device__ __forceinline__ float4 unp4(uint2 u) {
  return make_float4(
      __half2float(__ushort_as_half((unsigned short)(u.x & 0xffffu))),
      __half2float(__ushort_as_half((unsigned short)(u.x >> 16))),
      __half2float(__ushort_as_half((unsigned short)(u.y & 0xffffu))),
      __half2float(__ushort_as_half((unsigned short)(u.y >> 16))));
}

// ---------------- prep ----------------
__global__ void prep(const float* __restrict__ dWih, const float* __restrict__ dWhh,
                     const float* __restrict__ dbih, const float* __restrict__ dbhh,
                     const float* __restrict__ eWih, const float* __restrict__ eWhh,
                     const float* __restrict__ ebih, const float* __restrict__ ebhh,
                     const float* __restrict__ fcW,  const float* __restrict__ fcb,
                     char* __restrict__ wsb)
{
  int idx = blockIdx.x * 256 + threadIdx.x;
  if (idx < 25600) {                       // packed weight rows (pairs)
    int q = idx >> 9, t = idx & 511;
    unsigned w2p = 0, wdp = 0, wep = 0;
    if (t < 400) {
      int r = (t & 3) * 100 + (t >> 2);
      int j0 = 2 * q, j1 = 2 * q + 1;
      float wd0 = dWhh[r * 100 + j0], wd1 = dWhh[r * 100 + j1];
      float we0 = eWhh[r * 100 + j0], we1 = eWhh[r * 100 + j1];
      float s0 = 0.f, s1 = 0.f;
      for (int f = 0; f < 150; ++f) {
        float a = dWih[r * 150 + f];
        s0 = fmaf(a, fcW[f * 100 + j0], s0);
        s1 = fmaf(a, fcW[f * 100 + j1], s1);
      }
      w2p = pack2f(wd0 + s0, wd1 + s1);
      wdp = pack2f(wd0, wd1);
      wep = pack2f(we0, we1);
    }
    ((unsigned*)(wsb + B_W2P))[idx] = w2p;
    ((unsigned*)(wsb + B_WDP))[idx] = wdp;
    ((unsigned*)(wsb + B_WEP))[idx] = wep;
  } else if (idx < 25600 + 38400) {        // packed f16 enc_Wih
    int k = idx - 25600; int d = k >> 9, t = k & 511;
    unsigned pk = 0;
    if (t < 400) {
      int r = (t & 3) * 100 + (t >> 2);
      pk = pack2f(eWih[r * 150 + 2 * d], eWih[r * 150 + 2 * d + 1]);
    }
    ((unsigned*)(wsb + B_PIH))[k] = pk;
  } else if (idx < 25600 + 38400 + 512) {  // biases
    int t = idx - (25600 + 38400);
    float be = 0.f, b1 = 0.f, bf = 0.f;
    if (t < 400) {
      int r = (t & 3) * 100 + (t >> 2);
      be = ebih[r] + ebhh[r];
      b1 = dbih[r] + dbhh[r];
      float acc = 0.f;
      for (int f = 0; f < 150; ++f) acc = fmaf(dWih[r * 150 + f], fcb[f], acc);
      bf = b1 + acc;
    }
    ((float*)(wsb + B_BENC))[t] = be;
    ((float*)(wsb + B_B1))[t]   = b1;
    ((float*)(wsb + B_BEFF))[t] = bf;
  }
}

// ---------------- pre: xg[n][tl][g] = enc_Wih(f16) @ x_{tbase+tl}, tl<150 ----------------
__global__ __launch_bounds__(512, 4)
void pre(const float* __restrict__ x, const char* __restrict__ wsb,
         unsigned short* __restrict__ xg, int tbase)
{
  const int tid = threadIdx.x;
  const int n = blockIdx.x;
  __shared__ unsigned short xls[150 * 160];

  unsigned wih[75];
  const unsigned* pih = (const unsigned*)(wsb + B_PIH);
#pragma unroll
  for (int d = 0; d < 75; ++d) wih[d] = pih[(d << 9) + tid];

  const float* xb = x + (size_t)n * 45000;
  unsigned short* xgr = xg + (size_t)n * 60000 + ((tid < 400) ? tid : 0);
  const bool on = tid < 400;

  for (int d = tid; d < 150 * 160; d += 512) {
    int tl = d / 160, f = d - tl * 160;
    float v = 0.f;
    if (f < 150) {
      int c = f / 50, q = f - c * 50;
      v = xb[c * 15000 + (tbase + tl) * 50 + q];
    }
    xls[tl * 160 + f] = __half_as_ushort(__float2half(v));
  }
  __syncthreads();
  if (on) {
    for (int tl = 0; tl < 150; ++tl) {
      const uint4* row = (const uint4*)(xls + tl * 160);
      float a0 = 0.f, a1 = 0.f, a2 = 0.f, a3 = 0.f;
#pragma unroll
      for (int ch = 0; ch < 18; ++ch) {
        uint4 v = row[ch];
        a0 = fdot2u(wih[4 * ch + 0], v.x, a0);
        a1 = fdot2u(wih[4 * ch + 1], v.y, a1);
        a2 = fdot2u(wih[4 * ch + 2], v.z, a2);
        a3 = fdot2u(wih[4 * ch + 3], v.w, a3);
      }
      uint4 v = row[18];
      a0 = fdot2u(wih[72], v.x, a0);
      a1 = fdot2u(wih[73], v.y, a1);
      a2 = fdot2u(wih[74], v.z, a2);
      float a = (a0 + a1) + (a2 + a3);
      xgr[(size_t)tl * 400] = __half_as_ushort(__float2half(a));
    }
  }
}

// ---------------- recurrent: 1 thread = 1 LSTM cell (all 4 gates local) ----------------
// 128 threads (2 waves), thread j<100 owns cell j: wq[50] uint4 = 200 weight VGPRs.
// phase 0: encoder steps 0..149, park (h149,c149). phase 1: restore, enc 150..299 + 299 dec.
__global__ __launch_bounds__(128)
void recurrent(const unsigned short* __restrict__ xg, char* __restrict__ wsb, int phase)
{
  const int j = threadIdx.x;
  const int n = blockIdx.x;
  const int jj = (j < 100) ? j : 0;
  const bool act = j < 100;
  __shared__ unsigned short hh[2][112];

  const unsigned* WEP = (const unsigned*)(wsb + B_WEP);
  const unsigned* WDP = (const unsigned*)(wsb + B_WDP);
  const unsigned* W2P = (const unsigned*)(wsb + B_W2P);

  uint4 wq[50];
#pragma unroll
  for (int q = 0; q < 50; ++q) wq[q] = ((const uint4*)(WEP + (q << 9)))[j];

  const float4 benc4 = ((const float4*)(wsb + B_BENC))[j];
  unsigned short* histn = (unsigned short*)(wsb + B_HIST) + (size_t)n * HIST_STRIDE;
  float* stc = (float*)(histn + 128);   // 100 f32 carry-c at byte offset 256
  const unsigned short* xr = xg + (size_t)n * 60000 + 4 * jj;
  float c = 0.f;
  float hn = 0.f;

  if (phase == 0) {
    // prefetch xg rows 0,1 (uint2 = 4 gate inputs of cell j)
    uint2 xA = *(const uint2*)(xr);
    uint2 xB = *(const uint2*)(xr + 400);
    // encoder step 0 (h=0): a = benc + xg0
    {
      float4 xf = unp4(xA);
      float4 a = make_float4(benc4.x + xf.x, benc4.y + xf.y,
                             benc4.z + xf.z, benc4.w + xf.w);
      hn = cell_update(a, c);
      if (act) hh[1][j] = __half_as_ushort(__float2half(hn));
      __syncthreads();
      xA = xB;
      xB = *(const uint2*)(xr + 2 * 400);
    }
    // encoder steps 1..149 (xA = row ts, xB = row ts+1, prefetch ts+2)
    for (int ts = 1; ts < 150; ++ts) {
      uint2 xN = *(const uint2*)(xr + (size_t)((ts + 2 < 150) ? ts + 2 : 149) * 400);
      float4 a = dot4(hh[ts & 1], wq);
      float4 xf = unp4(xA);
      a.x += benc4.x + xf.x; a.y += benc4.y + xf.y;
      a.z += benc4.z + xf.z; a.w += benc4.w + xf.w;
      hn = cell_update(a, c);
      if (act) hh[(ts & 1) ^ 1][j] = __half_as_ushort(__float2half(hn));
      __syncthreads();
      xA = xB; xB = xN;
    }
    // park local state (h149, c149)
    if (act) {
      histn[j] = __half_as_ushort(__float2half(hn));
      stc[j] = c;
    }
    return;
  }

  // ---- phase 1: restore carry ----
  if (act) {
    hh[0][j] = histn[j];
    c = stc[j];
  }
  uint2 xA = *(const uint2*)(xr);
  uint2 xB = *(const uint2*)(xr + 400);
  __syncthreads();

  // encoder steps 150..299 (xg half-2 at local index ts-150)
  for (int ts = 150; ts < 300; ++ts) {
    const int li = ts - 150;
    uint2 xN = *(const uint2*)(xr + (size_t)((li + 2 < 150) ? li + 2 : 149) * 400);
    float4 a = dot4(hh[ts & 1], wq);
    float4 xf = unp4(xA);
    a.x += benc4.x + xf.x; a.y += benc4.y + xf.y;
    a.z += benc4.z + xf.z; a.w += benc4.w + xf.w;
    hn = cell_update(a, c);
    if (act) hh[(ts & 1) ^ 1][j] = __half_as_ushort(__float2half(hn));
    __syncthreads();
    xA = xB; xB = xN;
  }

  // decoder step 1: plain Whh (input zeros); enc h is in hh[0]
  const float4 b14 = ((const float4*)(wsb + B_B1))[j];
#pragma unroll
  for (int q = 0; q < 50; ++q) wq[q] = ((const uint4*)(WDP + (q << 9)))[j];
  {
    float4 a = dot4(hh[0], wq);
    a.x += b14.x; a.y += b14.y; a.z += b14.z; a.w += b14.w;
    hn = cell_update(a, c);
    if (act) {
      hh[1][j] = __half_as_ushort(__float2half(hn));
      histn[j] = __half_as_ushort(__float2half(hn));
    }
    __syncthreads();
  }
  // decoder steps 2..299: folded W2
  const float4 beff4 = ((const float4*)(wsb + B_BEFF))[j];
#pragma unroll
  for (int q = 0; q < 50; ++q) wq[q] = ((const uint4*)(W2P + (q << 9)))[j];
  for (int s = 2; s <= 299; ++s) {
    const int rd = (299 + s) & 1;
    float4 a = dot4(hh[rd], wq);
    a.x += beff4.x; a.y += beff4.y; a.z += beff4.z; a.w += beff4.w;
    hn = cell_update(a, c);
    if (act) {
      hh[rd ^ 1][j] = __half_as_ushort(__float2half(hn));
      histn[(s - 1) * 100 + j] = __half_as_ushort(__float2half(hn));
    }
    __syncthreads();
  }
}

// ---------------- emit: out[n][t] = fcW @ h_{t-1} + fcb ----------------
__global__ __launch_bounds__(192, 4)
void emit(const char* __restrict__ wsb, const float* __restrict__ fcW,
          const float* __restrict__ fcb, float* __restrict__ out)
{
  const int f = threadIdx.x;
  const int n = blockIdx.x;
  const int z = blockIdx.y;
  __shared__ unsigned short hl[15008];

  const uint4* src = (const uint4*)((const unsigned short*)(wsb + B_HIST) +
                                    (size_t)n * HIST_STRIDE + z * 15000);
  for (int k = f; k < 1875; k += 192) ((uint4*)hl)[k] = src[k];

  const bool on = f < 150;
  unsigned fw[50];
  float bias = 0.f;
  if (on) {
    const float* fp = fcW + f * 100;
#pragma unroll
    for (int q = 0; q < 50; ++q) fw[q] = pack2f(fp[2 * q], fp[2 * q + 1]);
    bias = fcb[f];
  }
  __syncthreads();

  if (!on) return;
  const int cc = f / 50, r = f - cc * 50;
  float* ob = out + (size_t)n * 45000 + cc * 15000 + r;
  if (z == 0) ob[0] = 0.f;
  const int rows = z ? 149 : 150;
  for (int tl = 0; tl < rows; ++tl) {
    const uint4* row = (const uint4*)(hl + tl * 100);
    float a0 = bias, a1 = 0.f, a2 = 0.f, a3 = 0.f;
#pragma unroll
    for (int ch = 0; ch < 12; ++ch) {
      uint4 v = row[ch];
      a0 = fdot2u(fw[4 * ch + 0], v.x, a0);
      a1 = fdot2u(fw[4 * ch + 1], v.y, a1);
      a2 = fdot2u(fw[4 * ch + 2], v.z, a2);
      a3 = fdot2u(fw[4 * ch + 3], v.w, a3);
    }
    uint2 v2 = *(const uint2*)(hl + tl * 100 + 96);
    a0 = fdot2u(fw[48], v2.x, a0);
    a1 = fdot2u(fw[49], v2.y, a1);
    const int tt = z * 150 + tl + 1;
    ob[tt * 50] = (a0 + a1) + (a2 + a3);
  }
}

extern "C" void kernel_launch(void* const* d_in, const int* in_sizes, int n_in,
                              void* d_out, int out_size, void* d_ws, size_t ws_size,
                              hipStream_t stream) {
  const float* x    = (const float*)d_in[0];
  const float* eWih = (const float*)d_in[1];
  const float* eWhh = (const float*)d_in[2];
  const float* ebih = (const float*)d_in[3];
  const float* ebhh = (const float*)d_in[4];
  const float* dWih = (const float*)d_in[5];
  const float* dWhh = (const float*)d_in[6];
  const float* dbih = (const float*)d_in[7];
  const float* dbhh = (const float*)d_in[8];
  const float* fcW  = (const float*)d_in[9];
  const float* fcb  = (const float*)d_in[10];
  float* out = (float*)d_out;
  char* wsb  = (char*)d_ws;

  unsigned short* xg = (unsigned short*)(wsb + B_XG);

  prep<<<252, 256, 0, stream>>>(dWih, dWhh, dbih, dbhh, eWih, eWhh, ebih, ebhh, fcW, fcb, wsb);
  // time-split halves: all 512 samples per recurrent dispatch, xg reused per half
  pre<<<512, 512, 0, stream>>>(x, wsb, xg, 0);
  recurrent<<<512, 128, 0, stream>>>(xg, wsb, 0);
  pre<<<512, 512, 0, stream>>>(x, wsb, xg, 150);
  recurrent<<<512, 128, 0, stream>>>(xg, wsb, 1);
  emit<<<dim3(512, 2), 192, 0, stream>>>(wsb, fcW, fcb, out);
}

// Round 4
// 1371.671 us; speedup vs baseline: 2.5152x; 2.5152x over previous
//
#include <hip/hip_runtime.h>
#include <hip/hip_fp16.h>

// N=512, C=3, T=300, V=25, M=2, F=150, H=100, gates=4H=400
// x element (n,c,t,v,m) at n*45000 + c*15000 + t*50 + (v*2+m)
// Weight-table column map: col t = 4*j + k  <->  gate-row k*100+j (k: 0=i,1=f,2=g,3=o)
// xg[n][tl][4*j+k] = gate k of cell j

// ws layout (BYTE offsets):
#define B_W2P   0u          // uint[50][512]  dec folded Whh+Wih@fcW, f16-pair packed
#define B_WDP   102400u     // uint[50][512]  dec Whh (step-1)
#define B_WEP   204800u     // uint[50][512]  enc Whh
#define B_PIH   307200u     // uint[75][512]  enc Wih f16 pairs
#define B_BENC  460800u     // float[512]
#define B_B1    462848u     // float[512]
#define B_BEFF  464896u     // float[512]
#define B_HIST  466944u     // ushort hist[512][29952]
#define HIST_STRIDE 29952
#define B_XG    31137792u   // ushort xg[512][150][400]
// Phase-0 carry state parked at head of each sample's hist region:
//   h149 (f16) at histn[0..99]; c149 (f32) at byte offset 256 (histn+128 ushorts).
// Overwritten only by decoder steps 1..4 of the same phase-1 block, before emit.

typedef _Float16 h2_t __attribute__((ext_vector_type(2)));

#if defined(__has_builtin)
#if __has_builtin(__builtin_amdgcn_fdot2)
#define HAS_FDOT2 1
#endif
#endif

__device__ __forceinline__ float fdot2u(unsigned a, unsigned b, float c) {
#ifdef HAS_FDOT2
  return __builtin_amdgcn_fdot2(__builtin_bit_cast(h2_t, a), __builtin_bit_cast(h2_t, b), c, false);
#else
  float al = __half2float(__ushort_as_half((unsigned short)(a & 0xffffu)));
  float ah = __half2float(__ushort_as_half((unsigned short)(a >> 16)));
  float bl = __half2float(__ushort_as_half((unsigned short)(b & 0xffffu)));
  float bh = __half2float(__ushort_as_half((unsigned short)(b >> 16)));
  return fmaf(ah, bh, fmaf(al, bl, c));
#endif
}

__device__ __forceinline__ unsigned pack2f(float a, float b) {
  return (unsigned)__half_as_ushort(__float2half(a)) |
         ((unsigned)__half_as_ushort(__float2half(b)) << 16);
}

__device__ __forceinline__ float fast_sig(float x) {
  float e = __builtin_amdgcn_exp2f(x * -1.442695040888963f);
  return __builtin_amdgcn_rcpf(1.f + e);
}
__device__ __forceinline__ float fast_tanh(float x) {
  float e = __builtin_amdgcn_exp2f(x * -2.885390081777926f);
  return fmaf(2.f, __builtin_amdgcn_rcpf(1.f + e), -1.f);
}

// 2-gate K=100 dot: 12 b128 + 1 b64 broadcast LDS reads, 100 fdot2.
// w[q].x -> gate A (i on even / f on odd), w[q].y -> gate B (g / o)
__device__ __forceinline__ float2 dot2g(const unsigned short* hb, const uint2 (&w)[50]) {
  const uint4* h4 = (const uint4*)hb;
  float a0 = 0.f, a1 = 0.f, b0 = 0.f, b1 = 0.f;
#pragma unroll
  for (int ch = 0; ch < 12; ++ch) {
    uint4 hv = h4[ch];
    a0 = fdot2u(w[4 * ch + 0].x, hv.x, a0);
    b0 = fdot2u(w[4 * ch + 0].y, hv.x, b0);
    a1 = fdot2u(w[4 * ch + 1].x, hv.y, a1);
    b1 = fdot2u(w[4 * ch + 1].y, hv.y, b1);
    a0 = fdot2u(w[4 * ch + 2].x, hv.z, a0);
    b0 = fdot2u(w[4 * ch + 2].y, hv.z, b0);
    a1 = fdot2u(w[4 * ch + 3].x, hv.w, a1);
    b1 = fdot2u(w[4 * ch + 3].y, hv.w, b1);
  }
  uint2 hv2 = *(const uint2*)(hb + 96);
  a0 = fdot2u(w[48].x, hv2.x, a0);
  b0 = fdot2u(w[48].y, hv2.x, b0);
  a1 = fdot2u(w[49].x, hv2.y, a1);
  b1 = fdot2u(w[49].y, hv2.y, b1);
  return make_float2(a0 + a1, b0 + b1);
}

// per-parity unpack of this pair's 2 gate inputs from the 4-gate uint2
__device__ __forceinline__ float2 unp2sel(uint2 u, int e) {
  unsigned a = e ? (u.x >> 16) : (u.x & 0xffffu);
  unsigned b = e ? (u.y >> 16) : (u.y & 0xffffu);
  return make_float2(__half2float(__ushort_as_half((unsigned short)a)),
                     __half2float(__ushort_as_half((unsigned short)b)));
}

// paired LSTM tail: pA,pB biased pre-activations.
// even lane: I=sig(pA), G=tanh(pB); odd lane: F=sig(pA), O=sig(pB).
// After 2 shuffles the EVEN lane holds the valid (c, h); odd lane garbage.
__device__ __forceinline__ float pair_tail(float pA, float pB, int e, float& c) {
  float actA = fast_sig(pA);
  float actB = e ? fast_sig(pB) : fast_tanh(pB);
  float vA = __shfl_xor(actA, 1);   // even receives F ; odd receives I
  float vB = __shfl_xor(actB, 1);   // even receives O ; odd receives G
  c = fmaf(vA, c, actA * actB);     // even: F*c + I*G   (odd: garbage)
  return vB * fast_tanh(c);         // even: O*tanh(c)   (odd: garbage)
}

// ---------------- prep ----------------
__global__ void prep(const float* __restrict__ dWih, const float* __restrict__ dWhh,
                     const float* __restrict__ dbih, const float* __restrict__ dbhh,
                     const float* __restrict__ eWih, const float* __restrict__ eWhh,
                     const float* __restrict__ ebih, const float* __restrict__ ebhh,
                     const float* __restrict__ fcW,  const float* __restrict__ fcb,
                     char* __restrict__ wsb)
{
  int idx = blockIdx.x * 256 + threadIdx.x;
  if (idx < 25600) {                       // packed weight rows (pairs)
    int q = idx >> 9, t = idx & 511;
    unsigned w2p = 0, wdp = 0, wep = 0;
    if (t < 400) {
      int r = (t & 3) * 100 + (t >> 2);
      int j0 = 2 * q, j1 = 2 * q + 1;
      float wd0 = dWhh[r * 100 + j0], wd1 = dWhh[r * 100 + j1];
      float we0 = eWhh[r * 100 + j0], we1 = eWhh[r * 100 + j1];
      float s0 = 0.f, s1 = 0.f;
      for (int f = 0; f < 150; ++f) {
        float a = dWih[r * 150 + f];
        s0 = fmaf(a, fcW[f * 100 + j0], s0);
        s1 = fmaf(a, fcW[f * 100 + j1], s1);
      }
      w2p = pack2f(wd0 + s0, wd1 + s1);
      wdp = pack2f(wd0, wd1);
      wep = pack2f(we0, we1);
    }
    ((unsigned*)(wsb + B_W2P))[idx] = w2p;
    ((unsigned*)(wsb + B_WDP))[idx] = wdp;
    ((unsigned*)(wsb + B_WEP))[idx] = wep;
  } else if (idx < 25600 + 38400) {        // packed f16 enc_Wih
    int k = idx - 25600; int d = k >> 9, t = k & 511;
    unsigned pk = 0;
    if (t < 400) {
      int r = (t & 3) * 100 + (t >> 2);
      pk = pack2f(eWih[r * 150 + 2 * d], eWih[r * 150 + 2 * d + 1]);
    }
    ((unsigned*)(wsb + B_PIH))[k] = pk;
  } else if (idx < 25600 + 38400 + 512) {  // biases
    int t = idx - (25600 + 38400);
    float be = 0.f, b1 = 0.f, bf = 0.f;
    if (t < 400) {
      int r = (t & 3) * 100 + (t >> 2);
      be = ebih[r] + ebhh[r];
      b1 = dbih[r] + dbhh[r];
      float acc = 0.f;
      for (int f = 0; f < 150; ++f) acc = fmaf(dWih[r * 150 + f], fcb[f], acc);
      bf = b1 + acc;
    }
    ((float*)(wsb + B_BENC))[t] = be;
    ((float*)(wsb + B_B1))[t]   = b1;
    ((float*)(wsb + B_BEFF))[t] = bf;
  }
}

// ---------------- pre: xg[n][tl][g] = enc_Wih(f16) @ x_{tbase+tl}, tl<150 ----------------
__global__ __launch_bounds__(512, 4)
void pre(const float* __restrict__ x, const char* __restrict__ wsb,
         unsigned short* __restrict__ xg, int tbase)
{
  const int tid = threadIdx.x;
  const int n = blockIdx.x;
  __shared__ unsigned short xls[150 * 160];

  unsigned wih[75];
  const unsigned* pih = (const unsigned*)(wsb + B_PIH);
#pragma unroll
  for (int d = 0; d < 75; ++d) wih[d] = pih[(d << 9) + tid];

  const float* xb = x + (size_t)n * 45000;
  unsigned short* xgr = xg + (size_t)n * 60000 + ((tid < 400) ? tid : 0);
  const bool on = tid < 400;

  for (int d = tid; d < 150 * 160; d += 512) {
    int tl = d / 160, f = d - tl * 160;
    float v = 0.f;
    if (f < 150) {
      int c = f / 50, q = f - c * 50;
      v = xb[c * 15000 + (tbase + tl) * 50 + q];
    }
    xls[tl * 160 + f] = __half_as_ushort(__float2half(v));
  }
  __syncthreads();
  if (on) {
    for (int tl = 0; tl < 150; ++tl) {
      const uint4* row = (const uint4*)(xls + tl * 160);
      float a0 = 0.f, a1 = 0.f, a2 = 0.f, a3 = 0.f;
#pragma unroll
      for (int ch = 0; ch < 18; ++ch) {
        uint4 v = row[ch];
        a0 = fdot2u(wih[4 * ch + 0], v.x, a0);
        a1 = fdot2u(wih[4 * ch + 1], v.y, a1);
        a2 = fdot2u(wih[4 * ch + 2], v.z, a2);
        a3 = fdot2u(wih[4 * ch + 3], v.w, a3);
      }
      uint4 v = row[18];
      a0 = fdot2u(wih[72], v.x, a0);
      a1 = fdot2u(wih[73], v.y, a1);
      a2 = fdot2u(wih[74], v.z, a2);
      float a = (a0 + a1) + (a2 + a3);
      xgr[(size_t)tl * 400] = __half_as_ushort(__float2half(a));
    }
  }
}

// ---------------- recurrent: 2 threads = 1 LSTM cell ----------------
// 256 threads (4 waves); pair (2j,2j+1) owns cell j<100 (threads 0..199 active).
// Even lane: gates (i,g); odd lane: (f,o). 100 weight VGPRs/thread -> no spill.
// phase 0: encoder steps 0..149, park (h149,c149). phase 1: restore, enc 150..299 + 299 dec.
__global__ __launch_bounds__(256)
void recurrent(const unsigned short* __restrict__ xg, char* __restrict__ wsb, int phase)
{
  const int tid = threadIdx.x;
  const int n = blockIdx.x;
  const int j = tid >> 1;           // cell index 0..127
  const int e = tid & 1;            // gate parity
  const int jj = (j < 100) ? j : 0;
  const bool act = j < 100;
  const bool even = act && (e == 0);
  __shared__ unsigned short hh[2][112];

  const unsigned* WEP = (const unsigned*)(wsb + B_WEP);
  const unsigned* WDP = (const unsigned*)(wsb + B_WDP);
  const unsigned* W2P = (const unsigned*)(wsb + B_W2P);

  uint2 wpp[50];
#pragma unroll
  for (int q = 0; q < 50; ++q) {
    uint4 w4 = ((const uint4*)(WEP + (q << 9)))[jj];
    wpp[q] = e ? make_uint2(w4.y, w4.w) : make_uint2(w4.x, w4.z);
  }

  float4 be4 = ((const float4*)(wsb + B_BENC))[jj];
  float bA = e ? be4.y : be4.x;
  float bB = e ? be4.w : be4.z;

  unsigned short* histn = (unsigned short*)(wsb + B_HIST) + (size_t)n * HIST_STRIDE;
  float* stc = (float*)(histn + 128);   // 100 f32 carry-c at byte offset 256
  const unsigned short* xr = xg + (size_t)n * 60000 + 4 * jj;
  float c = 0.f;
  float hn = 0.f;

  if (phase == 0) {
    uint2 xA = *(const uint2*)(xr);
    uint2 xB = *(const uint2*)(xr + 400);
    // encoder step 0 (h=0): a = benc + xg0
    {
      float2 xf = unp2sel(xA, e);
      hn = pair_tail(bA + xf.x, bB + xf.y, e, c);
      if (even) hh[1][j] = __half_as_ushort(__float2half(hn));
      __syncthreads();
      xA = xB;
      xB = *(const uint2*)(xr + 2 * 400);
    }
    // encoder steps 1..149 (xA = row ts, xB = ts+1, prefetch ts+2)
    for (int ts = 1; ts < 150; ++ts) {
      uint2 xN = *(const uint2*)(xr + (size_t)((ts + 2 < 150) ? ts + 2 : 149) * 400);
      float2 a = dot2g(hh[ts & 1], wpp);
      float2 xf = unp2sel(xA, e);
      hn = pair_tail(a.x + bA + xf.x, a.y + bB + xf.y, e, c);
      if (even) hh[(ts & 1) ^ 1][j] = __half_as_ushort(__float2half(hn));
      __syncthreads();
      xA = xB; xB = xN;
    }
    // park local state (h149, c149) — valid on even lanes
    if (even) {
      histn[j] = __half_as_ushort(__float2half(hn));
      stc[j] = c;
    }
    return;
  }

  // ---- phase 1: restore carry ----
  if (tid < 100) hh[0][tid] = histn[tid];
  if (even) c = stc[j];
  uint2 xA = *(const uint2*)(xr);
  uint2 xB = *(const uint2*)(xr + 400);
  __syncthreads();

  // encoder steps 150..299 (xg half-2 at local index ts-150)
  for (int ts = 150; ts < 300; ++ts) {
    const int li = ts - 150;
    uint2 xN = *(const uint2*)(xr + (size_t)((li + 2 < 150) ? li + 2 : 149) * 400);
    float2 a = dot2g(hh[ts & 1], wpp);
    float2 xf = unp2sel(xA, e);
    hn = pair_tail(a.x + bA + xf.x, a.y + bB + xf.y, e, c);
    if (even) hh[(ts & 1) ^ 1][j] = __half_as_ushort(__float2half(hn));
    __syncthreads();
    xA = xB; xB = xN;
  }

  // decoder step 1: plain Whh (input zeros); enc h is in hh[0]
  {
    float4 b14 = ((const float4*)(wsb + B_B1))[jj];
    bA = e ? b14.y : b14.x;
    bB = e ? b14.w : b14.z;
  }
#pragma unroll
  for (int q = 0; q < 50; ++q) {
    uint4 w4 = ((const uint4*)(WDP + (q << 9)))[jj];
    wpp[q] = e ? make_uint2(w4.y, w4.w) : make_uint2(w4.x, w4.z);
  }
  {
    float2 a = dot2g(hh[0], wpp);
    hn = pair_tail(a.x + bA, a.y + bB, e, c);
    if (even) {
      hh[1][j] = __half_as_ushort(__float2half(hn));
      histn[j] = __half_as_ushort(__float2half(hn));
    }
    __syncthreads();
  }
  // decoder steps 2..299: folded W2
  {
    float4 bf4 = ((const float4*)(wsb + B_BEFF))[jj];
    bA = e ? bf4.y : bf4.x;
    bB = e ? bf4.w : bf4.z;
  }
#pragma unroll
  for (int q = 0; q < 50; ++q) {
    uint4 w4 = ((const uint4*)(W2P + (q << 9)))[jj];
    wpp[q] = e ? make_uint2(w4.y, w4.w) : make_uint2(w4.x, w4.z);
  }
  for (int s = 2; s <= 299; ++s) {
    const int rd = (299 + s) & 1;
    float2 a = dot2g(hh[rd], wpp);
    hn = pair_tail(a.x + bA, a.y + bB, e, c);
    if (even) {
      hh[rd ^ 1][j] = __half_as_ushort(__float2half(hn));
      histn[(s - 1) * 100 + j] = __half_as_ushort(__float2half(hn));
    }
    __syncthreads();
  }
}

// ---------------- emit: out[n][t] = fcW @ h_{t-1} + fcb ----------------
__global__ __launch_bounds__(192, 4)
void emit(const char* __restrict__ wsb, const float* __restrict__ fcW,
          const float* __restrict__ fcb, float* __restrict__ out)
{
  const int f = threadIdx.x;
  const int n = blockIdx.x;
  const int z = blockIdx.y;
  __shared__ unsigned short hl[15008];

  const uint4* src = (const uint4*)((const unsigned short*)(wsb + B_HIST) +
                                    (size_t)n * HIST_STRIDE + z * 15000);
  for (int k = f; k < 1875; k += 192) ((uint4*)hl)[k] = src[k];

  const bool on = f < 150;
  unsigned fw[50];
  float bias = 0.f;
  if (on) {
    const float* fp = fcW + f * 100;
#pragma unroll
    for (int q = 0; q < 50; ++q) fw[q] = pack2f(fp[2 * q], fp[2 * q + 1]);
    bias = fcb[f];
  }
  __syncthreads();

  if (!on) return;
  const int cc = f / 50, r = f - cc * 50;
  float* ob = out + (size_t)n * 45000 + cc * 15000 + r;
  if (z == 0) ob[0] = 0.f;
  const int rows = z ? 149 : 150;
  for (int tl = 0; tl < rows; ++tl) {
    const uint4* row = (const uint4*)(hl + tl * 100);
    float a0 = bias, a1 = 0.f, a2 = 0.f, a3 = 0.f;
#pragma unroll
    for (int ch = 0; ch < 12; ++ch) {
      uint4 v = row[ch];
      a0 = fdot2u(fw[4 * ch + 0], v.x, a0);
      a1 = fdot2u(fw[4 * ch + 1], v.y, a1);
      a2 = fdot2u(fw[4 * ch + 2], v.z, a2);
      a3 = fdot2u(fw[4 * ch + 3], v.w, a3);
    }
    uint2 v2 = *(const uint2*)(hl + tl * 100 + 96);
    a0 = fdot2u(fw[48], v2.x, a0);
    a1 = fdot2u(fw[49], v2.y, a1);
    const int tt = z * 150 + tl + 1;
    ob[tt * 50] = (a0 + a1) + (a2 + a3);
  }
}

extern "C" void kernel_launch(void* const* d_in, const int* in_sizes, int n_in,
                              void* d_out, int out_size, void* d_ws, size_t ws_size,
                              hipStream_t stream) {
  const float* x    = (const float*)d_in[0];
  const float* eWih = (const float*)d_in[1];
  const float* eWhh = (const float*)d_in[2];
  const float* ebih = (const float*)d_in[3];
  const float* ebhh = (const float*)d_in[4];
  const float* dWih = (const float*)d_in[5];
  const float* dWhh = (const float*)d_in[6];
  const float* dbih = (const float*)d_in[7];
  const float* dbhh = (const float*)d_in[8];
  const float* fcW  = (const float*)d_in[9];
  const float* fcb  = (const float*)d_in[10];
  float* out = (float*)d_out;
  char* wsb  = (char*)d_ws;

  unsigned short* xg = (unsigned short*)(wsb + B_XG);

  prep<<<252, 256, 0, stream>>>(dWih, dWhh, dbih, dbhh, eWih, eWhh, ebih, ebhh, fcW, fcb, wsb);
  // time-split halves: all 512 samples per recurrent dispatch, xg reused per half
  pre<<<512, 512, 0, stream>>>(x, wsb, xg, 0);
  recurrent<<<512, 256, 0, stream>>>(xg, wsb, 0);
  pre<<<512, 512, 0, stream>>>(x, wsb, xg, 150);
  recurrent<<<512, 256, 0, stream>>>(xg, wsb, 1);
  emit<<<dim3(512, 2), 192, 0, stream>>>(wsb, fcW, fcb, out);
}

// Round 5
// 1357.297 us; speedup vs baseline: 2.5418x; 1.0106x over previous
//
#include <hip/hip_runtime.h>
#include <hip/hip_fp16.h>

// N=512, C=3, T=300, V=25, M=2, F=150, H=100, gates=4H=400
// x element (n,c,t,v,m) at n*45000 + c*15000 + t*50 + (v*2+m)
// Weight-table column map: col = 4*j + k  <->  gate-row k*100+j (k: 0=i,1=f,2=g,3=o)
// xg[n][tl][4*j+k] = gate k of cell j

// ws layout (BYTE offsets):
#define B_W2P   0u          // uint[50][512]  dec folded Whh+Wih@fcW, f16-pair packed
#define B_WDP   102400u     // uint[50][512]  dec Whh (step-1)
#define B_WEP   204800u     // uint[50][512]  enc Whh
#define B_PIH   307200u     // uint[75][512]  enc Wih f16 pairs
#define B_BENC  460800u     // float[512]
#define B_B1    462848u     // float[512]
#define B_BEFF  464896u     // float[512]
#define B_HIST  466944u     // ushort hist[512][29952]
#define HIST_STRIDE 29952
#define B_XG    31137792u   // ushort xg[512][150][400]
// Phase-0 carry state parked at head of each sample's hist region:
//   h149 (f16) at histn[0..99]; c149 (f32) at byte offset 256 (histn+128 ushorts).
// Overwritten only by decoder steps 1..4 of the same phase-1 dispatch, before emit.

typedef _Float16 h2_t __attribute__((ext_vector_type(2)));
typedef _Float16 f16x8 __attribute__((ext_vector_type(8)));
typedef float f32x4v __attribute__((ext_vector_type(4)));

#if defined(__has_builtin)
#if __has_builtin(__builtin_amdgcn_fdot2)
#define HAS_FDOT2 1
#endif
#endif

__device__ __forceinline__ float fdot2u(unsigned a, unsigned b, float c) {
#ifdef HAS_FDOT2
  return __builtin_amdgcn_fdot2(__builtin_bit_cast(h2_t, a), __builtin_bit_cast(h2_t, b), c, false);
#else
  float al = __half2float(__ushort_as_half((unsigned short)(a & 0xffffu)));
  float ah = __half2float(__ushort_as_half((unsigned short)(a >> 16)));
  float bl = __half2float(__ushort_as_half((unsigned short)(b & 0xffffu)));
  float bh = __half2float(__ushort_as_half((unsigned short)(b >> 16)));
  return fmaf(ah, bh, fmaf(al, bl, c));
#endif
}

__device__ __forceinline__ unsigned pack2f(float a, float b) {
  return (unsigned)__half_as_ushort(__float2half(a)) |
         ((unsigned)__half_as_ushort(__float2half(b)) << 16);
}

__device__ __forceinline__ float fast_sig(float x) {
  float e = __builtin_amdgcn_exp2f(x * -1.442695040888963f);
  return __builtin_amdgcn_rcpf(1.f + e);
}
__device__ __forceinline__ float fast_tanh(float x) {
  float e = __builtin_amdgcn_exp2f(x * -2.885390081777926f);
  return fmaf(2.f, __builtin_amdgcn_rcpf(1.f + e), -1.f);
}

__device__ __forceinline__ float4 unp4(uint2 u) {
  return make_float4(
      __half2float(__ushort_as_half((unsigned short)(u.x & 0xffffu))),
      __half2float(__ushort_as_half((unsigned short)(u.x >> 16))),
      __half2float(__ushort_as_half((unsigned short)(u.y & 0xffffu))),
      __half2float(__ushort_as_half((unsigned short)(u.y >> 16))));
}

__device__ __forceinline__ f32x4v mfma16(uint4 a, uint4 b, f32x4v c) {
  return __builtin_amdgcn_mfma_f32_16x16x32_f16(
      __builtin_bit_cast(f16x8, a), __builtin_bit_cast(f16x8, b), c, 0, 0, 0);
}

// A-fragment gather: A[m][k] = W-table element; lane holds m = 16*ti + s,
// k = 32*kk + 8*q + j (j=0..7). Table rows q' = k/2 valid for q' < 50.
__device__ __forceinline__ void gatherA(const unsigned* W, int w, int s, int q,
                                        uint4 (&af)[5][4]) {
#pragma unroll
  for (int i = 0; i < 5; ++i) {
    const int col = (5 * w + i) * 16 + s;
#pragma unroll
    for (int kk = 0; kk < 4; ++kk) {
      const int q0 = kk * 16 + q * 4;
      unsigned e0 = (q0 + 0 < 50) ? W[(q0 + 0) * 512 + col] : 0u;
      unsigned e1 = (q0 + 1 < 50) ? W[(q0 + 1) * 512 + col] : 0u;
      unsigned e2 = (q0 + 2 < 50) ? W[(q0 + 2) * 512 + col] : 0u;
      unsigned e3 = (q0 + 3 < 50) ? W[(q0 + 3) * 512 + col] : 0u;
      af[i][kk] = make_uint4(e0, e1, e2, e3);
    }
  }
}

// ---------------- prep ----------------
__global__ void prep(const float* __restrict__ dWih, const float* __restrict__ dWhh,
                     const float* __restrict__ dbih, const float* __restrict__ dbhh,
                     const float* __restrict__ eWih, const float* __restrict__ eWhh,
                     const float* __restrict__ ebih, const float* __restrict__ ebhh,
                     const float* __restrict__ fcW,  const float* __restrict__ fcb,
                     char* __restrict__ wsb)
{
  int idx = blockIdx.x * 256 + threadIdx.x;
  if (idx < 25600) {                       // packed weight rows (pairs)
    int q = idx >> 9, t = idx & 511;
    unsigned w2p = 0, wdp = 0, wep = 0;
    if (t < 400) {
      int r = (t & 3) * 100 + (t >> 2);
      int j0 = 2 * q, j1 = 2 * q + 1;
      float wd0 = dWhh[r * 100 + j0], wd1 = dWhh[r * 100 + j1];
      float we0 = eWhh[r * 100 + j0], we1 = eWhh[r * 100 + j1];
      float s0 = 0.f, s1 = 0.f;
      for (int f = 0; f < 150; ++f) {
        float a = dWih[r * 150 + f];
        s0 = fmaf(a, fcW[f * 100 + j0], s0);
        s1 = fmaf(a, fcW[f * 100 + j1], s1);
      }
      w2p = pack2f(wd0 + s0, wd1 + s1);
      wdp = pack2f(wd0, wd1);
      wep = pack2f(we0, we1);
    }
    ((unsigned*)(wsb + B_W2P))[idx] = w2p;
    ((unsigned*)(wsb + B_WDP))[idx] = wdp;
    ((unsigned*)(wsb + B_WEP))[idx] = wep;
  } else if (idx < 25600 + 38400) {        // packed f16 enc_Wih
    int k = idx - 25600; int d = k >> 9, t = k & 511;
    unsigned pk = 0;
    if (t < 400) {
      int r = (t & 3) * 100 + (t >> 2);
      pk = pack2f(eWih[r * 150 + 2 * d], eWih[r * 150 + 2 * d + 1]);
    }
    ((unsigned*)(wsb + B_PIH))[k] = pk;
  } else if (idx < 25600 + 38400 + 512) {  // biases
    int t = idx - (25600 + 38400);
    float be = 0.f, b1 = 0.f, bf = 0.f;
    if (t < 400) {
      int r = (t & 3) * 100 + (t >> 2);
      be = ebih[r] + ebhh[r];
      b1 = dbih[r] + dbhh[r];
      float acc = 0.f;
      for (int f = 0; f < 150; ++f) acc = fmaf(dWih[r * 150 + f], fcb[f], acc);
      bf = b1 + acc;
    }
    ((float*)(wsb + B_BENC))[t] = be;
    ((float*)(wsb + B_B1))[t]   = b1;
    ((float*)(wsb + B_BEFF))[t] = bf;
  }
}

// ---------------- pre: xg[n][tl][g] = enc_Wih(f16) @ x_{tbase+tl}, tl<150 ----------------
__global__ __launch_bounds__(512, 4)
void pre(const float* __restrict__ x, const char* __restrict__ wsb,
         unsigned short* __restrict__ xg, int tbase)
{
  const int tid = threadIdx.x;
  const int n = blockIdx.x;
  __shared__ unsigned short xls[150 * 160];

  unsigned wih[75];
  const unsigned* pih = (const unsigned*)(wsb + B_PIH);
#pragma unroll
  for (int d = 0; d < 75; ++d) wih[d] = pih[(d << 9) + tid];

  const float* xb = x + (size_t)n * 45000;
  unsigned short* xgr = xg + (size_t)n * 60000 + ((tid < 400) ? tid : 0);
  const bool on = tid < 400;

  for (int d = tid; d < 150 * 160; d += 512) {
    int tl = d / 160, f = d - tl * 160;
    float v = 0.f;
    if (f < 150) {
      int c = f / 50, q = f - c * 50;
      v = xb[c * 15000 + (tbase + tl) * 50 + q];
    }
    xls[tl * 160 + f] = __half_as_ushort(__float2half(v));
  }
  __syncthreads();
  if (on) {
    for (int tl = 0; tl < 150; ++tl) {
      const uint4* row = (const uint4*)(xls + tl * 160);
      float a0 = 0.f, a1 = 0.f, a2 = 0.f, a3 = 0.f;
#pragma unroll
      for (int ch = 0; ch < 18; ++ch) {
        uint4 v = row[ch];
        a0 = fdot2u(wih[4 * ch + 0], v.x, a0);
        a1 = fdot2u(wih[4 * ch + 1], v.y, a1);
        a2 = fdot2u(wih[4 * ch + 2], v.z, a2);
        a3 = fdot2u(wih[4 * ch + 3], v.w, a3);
      }
      uint4 v = row[18];
      a0 = fdot2u(wih[72], v.x, a0);
      a1 = fdot2u(wih[73], v.y, a1);
      a2 = fdot2u(wih[74], v.z, a2);
      float a = (a0 + a1) + (a2 + a3);
      xgr[(size_t)tl * 400] = __half_as_ushort(__float2half(a));
    }
  }
}

// ---------------- recurrent: MFMA, 16 samples/block, 32 blocks, 5 waves ----------------
// gates(400 x 100) @ h(100 x 16) per step as 25 M-tiles x 4 K-steps of
// mfma_f32_16x16x32_f16. Lane (s=lane&15, q=lane>>4); wave w owns M-tiles 5w..5w+4.
// D-frag: lane holds rows 4q..4q+3 of its tile = gates (i,f,g,o) of cell 4*ti+q,
// col s = sample -> LSTM tail is fully lane-local (no shuffles).
// B-frag (h): one ds_read_b128 per K-step per lane, shared across all M-tiles.
__global__ __launch_bounds__(320)
void recurrent(const unsigned short* __restrict__ xg, char* __restrict__ wsb, int phase)
{
  const int tid  = threadIdx.x;
  const int w    = tid >> 6;        // wave 0..4
  const int lane = tid & 63;
  const int s    = lane & 15;       // sample within block
  const int q    = lane >> 4;       // 0..3
  const int nb   = blockIdx.x * 16;
  const int n    = nb + s;

  __shared__ unsigned short hT[2][16][136];  // [buf][sample][k(128)+pad], f16

  // zero both buffers (covers K-pad rows 100..127 and initial h=0)
  for (int k = tid; k < 2 * 16 * 136; k += 320) ((unsigned short*)hT)[k] = 0;

  const unsigned* WEP = (const unsigned*)(wsb + B_WEP);
  const unsigned* WDP = (const unsigned*)(wsb + B_WDP);
  const unsigned* W2P = (const unsigned*)(wsb + B_W2P);

  uint4 af[5][4];
  gatherA(WEP, w, s, q, af);

  // per-cell constants: cell(i) = 4*(5w+i) + q
  int cells[5];
  float4 be[5];
#pragma unroll
  for (int i = 0; i < 5; ++i) {
    cells[i] = 4 * (5 * w + i) + q;
    be[i] = ((const float4*)(wsb + B_BENC))[cells[i]];
  }

  unsigned short* histn = (unsigned short*)(wsb + B_HIST) + (size_t)n * HIST_STRIDE;
  float* stcn = (float*)(histn + 128);  // 100 f32 carry-c at byte offset 256
  const unsigned short* xrow = xg + (size_t)n * 60000;
  int xco[5];
#pragma unroll
  for (int i = 0; i < 5; ++i) xco[i] = 4 * cells[i];  // ushort offset of cell's 4 gates

  float cst[5] = {0.f, 0.f, 0.f, 0.f, 0.f};
  float hl[5]  = {0.f, 0.f, 0.f, 0.f, 0.f};

  if (phase == 0) {
    __syncthreads();  // LDS zeros visible
    uint2 xA[5], xB[5];
#pragma unroll
    for (int i = 0; i < 5; ++i) {
      xA[i] = *(const uint2*)(xrow + 0 * 400 + xco[i]);
      xB[i] = *(const uint2*)(xrow + 1 * 400 + xco[i]);
    }
    for (int ts = 0; ts < 150; ++ts) {
      const int rd = ts & 1;
      const int tn = (ts + 2 < 150) ? ts + 2 : 149;
      uint2 xN[5];
#pragma unroll
      for (int i = 0; i < 5; ++i) xN[i] = *(const uint2*)(xrow + (size_t)tn * 400 + xco[i]);
      f32x4v acc[5];
#pragma unroll
      for (int i = 0; i < 5; ++i) {
        float4 xf = unp4(xA[i]);
        acc[i][0] = be[i].x + xf.x; acc[i][1] = be[i].y + xf.y;
        acc[i][2] = be[i].z + xf.z; acc[i][3] = be[i].w + xf.w;
      }
#pragma unroll
      for (int kk = 0; kk < 4; ++kk) {
        uint4 b = *(const uint4*)(&hT[rd][s][kk * 32 + q * 8]);
#pragma unroll
        for (int i = 0; i < 5; ++i) acc[i] = mfma16(af[i][kk], b, acc[i]);
      }
#pragma unroll
      for (int i = 0; i < 5; ++i) {
        float ii = fast_sig(acc[i][0]), ff = fast_sig(acc[i][1]);
        float gg = fast_tanh(acc[i][2]), oo = fast_sig(acc[i][3]);
        cst[i] = fmaf(ff, cst[i], ii * gg);
        hl[i] = oo * fast_tanh(cst[i]);
        hT[rd ^ 1][s][cells[i]] = __half_as_ushort(__float2half(hl[i]));
      }
      __syncthreads();
#pragma unroll
      for (int i = 0; i < 5; ++i) { xA[i] = xB[i]; xB[i] = xN[i]; }
    }
    // park (h149, c149)
#pragma unroll
    for (int i = 0; i < 5; ++i) {
      histn[cells[i]] = __half_as_ushort(__float2half(hl[i]));
      stcn[cells[i]]  = cst[i];
    }
    return;
  }

  // ---- phase 1: restore carry into hT[0] (ts=150 reads rd=0) ----
  __syncthreads();  // zeros visible before restore writes
#pragma unroll
  for (int i = 0; i < 5; ++i) {
    hT[0][s][cells[i]] = histn[cells[i]];
    cst[i] = stcn[cells[i]];
  }
  uint2 xA[5], xB[5];
#pragma unroll
  for (int i = 0; i < 5; ++i) {
    xA[i] = *(const uint2*)(xrow + 0 * 400 + xco[i]);
    xB[i] = *(const uint2*)(xrow + 1 * 400 + xco[i]);
  }
  __syncthreads();

  // encoder steps 150..299 (xg half-2 at local index ts-150)
  for (int ts = 150; ts < 300; ++ts) {
    const int rd = ts & 1;
    const int li = ts - 150;
    const int tn = (li + 2 < 150) ? li + 2 : 149;
    uint2 xN[5];
#pragma unroll
    for (int i = 0; i < 5; ++i) xN[i] = *(const uint2*)(xrow + (size_t)tn * 400 + xco[i]);
    f32x4v acc[5];
#pragma unroll
    for (int i = 0; i < 5; ++i) {
      float4 xf = unp4(xA[i]);
      acc[i][0] = be[i].x + xf.x; acc[i][1] = be[i].y + xf.y;
      acc[i][2] = be[i].z + xf.z; acc[i][3] = be[i].w + xf.w;
    }
#pragma unroll
    for (int kk = 0; kk < 4; ++kk) {
      uint4 b = *(const uint4*)(&hT[rd][s][kk * 32 + q * 8]);
#pragma unroll
      for (int i = 0; i < 5; ++i) acc[i] = mfma16(af[i][kk], b, acc[i]);
    }
#pragma unroll
    for (int i = 0; i < 5; ++i) {
      float ii = fast_sig(acc[i][0]), ff = fast_sig(acc[i][1]);
      float gg = fast_tanh(acc[i][2]), oo = fast_sig(acc[i][3]);
      cst[i] = fmaf(ff, cst[i], ii * gg);
      float h = oo * fast_tanh(cst[i]);
      hT[rd ^ 1][s][cells[i]] = __half_as_ushort(__float2half(h));
    }
    __syncthreads();
#pragma unroll
    for (int i = 0; i < 5; ++i) { xA[i] = xB[i]; xB[i] = xN[i]; }
  }

  // decoder step 1: plain Whh (input zeros); enc h is in hT[0]
  gatherA(WDP, w, s, q, af);
  float4 bb[5];
#pragma unroll
  for (int i = 0; i < 5; ++i) bb[i] = ((const float4*)(wsb + B_B1))[cells[i]];
  {
    f32x4v acc[5];
#pragma unroll
    for (int i = 0; i < 5; ++i) {
      acc[i][0] = bb[i].x; acc[i][1] = bb[i].y;
      acc[i][2] = bb[i].z; acc[i][3] = bb[i].w;
    }
#pragma unroll
    for (int kk = 0; kk < 4; ++kk) {
      uint4 b = *(const uint4*)(&hT[0][s][kk * 32 + q * 8]);
#pragma unroll
      for (int i = 0; i < 5; ++i) acc[i] = mfma16(af[i][kk], b, acc[i]);
    }
#pragma unroll
    for (int i = 0; i < 5; ++i) {
      float ii = fast_sig(acc[i][0]), ff = fast_sig(acc[i][1]);
      float gg = fast_tanh(acc[i][2]), oo = fast_sig(acc[i][3]);
      cst[i] = fmaf(ff, cst[i], ii * gg);
      float h = oo * fast_tanh(cst[i]);
      hT[1][s][cells[i]] = __half_as_ushort(__float2half(h));
      histn[cells[i]] = __half_as_ushort(__float2half(h));
    }
    __syncthreads();
  }
  // decoder steps 2..299: folded W2
  gatherA(W2P, w, s, q, af);
#pragma unroll
  for (int i = 0; i < 5; ++i) bb[i] = ((const float4*)(wsb + B_BEFF))[cells[i]];
  for (int st = 2; st <= 299; ++st) {
    const int rd = (299 + st) & 1;
    f32x4v acc[5];
#pragma unroll
    for (int i = 0; i < 5; ++i) {
      acc[i][0] = bb[i].x; acc[i][1] = bb[i].y;
      acc[i][2] = bb[i].z; acc[i][3] = bb[i].w;
    }
#pragma unroll
    for (int kk = 0; kk < 4; ++kk) {
      uint4 b = *(const uint4*)(&hT[rd][s][kk * 32 + q * 8]);
#pragma unroll
      for (int i = 0; i < 5; ++i) acc[i] = mfma16(af[i][kk], b, acc[i]);
    }
#pragma unroll
    for (int i = 0; i < 5; ++i) {
      float ii = fast_sig(acc[i][0]), ff = fast_sig(acc[i][1]);
      float gg = fast_tanh(acc[i][2]), oo = fast_sig(acc[i][3]);
      cst[i] = fmaf(ff, cst[i], ii * gg);
      float h = oo * fast_tanh(cst[i]);
      hT[rd ^ 1][s][cells[i]] = __half_as_ushort(__float2half(h));
      histn[(st - 1) * 100 + cells[i]] = __half_as_ushort(__float2half(h));
    }
    __syncthreads();
  }
}

// ---------------- emit: out[n][t] = fcW @ h_{t-1} + fcb ----------------
__global__ __launch_bounds__(192, 4)
void emit(const char* __restrict__ wsb, const float* __restrict__ fcW,
          const float* __restrict__ fcb, float* __restrict__ out)
{
  const int f = threadIdx.x;
  const int n = blockIdx.x;
  const int z = blockIdx.y;
  __shared__ unsigned short hl[15008];

  const uint4* src = (const uint4*)((const unsigned short*)(wsb + B_HIST) +
                                    (size_t)n * HIST_STRIDE + z * 15000);
  for (int k = f; k < 1875; k += 192) ((uint4*)hl)[k] = src[k];

  const bool on = f < 150;
  unsigned fw[50];
  float bias = 0.f;
  if (on) {
    const float* fp = fcW + f * 100;
#pragma unroll
    for (int q = 0; q < 50; ++q) fw[q] = pack2f(fp[2 * q], fp[2 * q + 1]);
    bias = fcb[f];
  }
  __syncthreads();

  if (!on) return;
  const int cc = f / 50, r = f - cc * 50;
  float* ob = out + (size_t)n * 45000 + cc * 15000 + r;
  if (z == 0) ob[0] = 0.f;
  const int rows = z ? 149 : 150;
  for (int tl = 0; tl < rows; ++tl) {
    const uint4* row = (const uint4*)(hl + tl * 100);
    float a0 = bias, a1 = 0.f, a2 = 0.f, a3 = 0.f;
#pragma unroll
    for (int ch = 0; ch < 12; ++ch) {
      uint4 v = row[ch];
      a0 = fdot2u(fw[4 * ch + 0], v.x, a0);
      a1 = fdot2u(fw[4 * ch + 1], v.y, a1);
      a2 = fdot2u(fw[4 * ch + 2], v.z, a2);
      a3 = fdot2u(fw[4 * ch + 3], v.w, a3);
    }
    uint2 v2 = *(const uint2*)(hl + tl * 100 + 96);
    a0 = fdot2u(fw[48], v2.x, a0);
    a1 = fdot2u(fw[49], v2.y, a1);
    const int tt = z * 150 + tl + 1;
    ob[tt * 50] = (a0 + a1) + (a2 + a3);
  }
}

extern "C" void kernel_launch(void* const* d_in, const int* in_sizes, int n_in,
                              void* d_out, int out_size, void* d_ws, size_t ws_size,
                              hipStream_t stream) {
  const float* x    = (const float*)d_in[0];
  const float* eWih = (const float*)d_in[1];
  const float* eWhh = (const float*)d_in[2];
  const float* ebih = (const float*)d_in[3];
  const float* ebhh = (const float*)d_in[4];
  const float* dWih = (const float*)d_in[5];
  const float* dWhh = (const float*)d_in[6];
  const float* dbih = (const float*)d_in[7];
  const float* dbhh = (const float*)d_in[8];
  const float* fcW  = (const float*)d_in[9];
  const float* fcb  = (const float*)d_in[10];
  float* out = (float*)d_out;
  char* wsb  = (char*)d_ws;

  unsigned short* xg = (unsigned short*)(wsb + B_XG);

  prep<<<252, 256, 0, stream>>>(dWih, dWhh, dbih, dbhh, eWih, eWhh, ebih, ebhh, fcW, fcb, wsb);
  // time-split halves: all 512 samples per recurrent dispatch (32 blocks x 16 samples)
  pre<<<512, 512, 0, stream>>>(x, wsb, xg, 0);
  recurrent<<<32, 320, 0, stream>>>(xg, wsb, 0);
  pre<<<512, 512, 0, stream>>>(x, wsb, xg, 150);
  recurrent<<<32, 320, 0, stream>>>(xg, wsb, 1);
  emit<<<dim3(512, 2), 192, 0, stream>>>(wsb, fcW, fcb, out);
}

// Round 6
// 1199.818 us; speedup vs baseline: 2.8754x; 1.1313x over previous
//
#include <hip/hip_runtime.h>
#include <hip/hip_fp16.h>

// N=512, C=3, T=300, V=25, M=2, F=150, H=100, gates=4H=400
// x element (n,c,t,v,m) at n*45000 + c*15000 + t*50 + (v*2+m)
// Weight-table column map: col = 4*j + k  <->  gate-row k*100+j (k: 0=i,1=f,2=g,3=o)
// Fused-K recurrence: gates = [Whh | Wih] @ [h ; x_t] + b, K = 256 (h:0..99, x:100..249, pad)

// ws layout (BYTE offsets):
#define B_W2P   0u          // uint[50][512]  dec folded Whh+Wih@fcW, f16-pair packed
#define B_WDP   102400u     // uint[50][512]  dec Whh (step-1)
#define B_WEP   204800u     // uint[50][512]  enc Whh
#define B_PIH   307200u     // uint[75][512]  enc Wih f16 pairs (K-pairs 50..124 of fused K)
#define B_BENC  460800u     // float[512]
#define B_B1    462848u     // float[512]
#define B_BEFF  464896u     // float[512]
#define B_HIST  466944u     // ushort hist[512][29952]
#define HIST_STRIDE 29952

typedef _Float16 h2_t __attribute__((ext_vector_type(2)));
typedef _Float16 f16x8 __attribute__((ext_vector_type(8)));
typedef float f32x4v __attribute__((ext_vector_type(4)));

#if defined(__has_builtin)
#if __has_builtin(__builtin_amdgcn_fdot2)
#define HAS_FDOT2 1
#endif
#endif

__device__ __forceinline__ float fdot2u(unsigned a, unsigned b, float c) {
#ifdef HAS_FDOT2
  return __builtin_amdgcn_fdot2(__builtin_bit_cast(h2_t, a), __builtin_bit_cast(h2_t, b), c, false);
#else
  float al = __half2float(__ushort_as_half((unsigned short)(a & 0xffffu)));
  float ah = __half2float(__ushort_as_half((unsigned short)(a >> 16)));
  float bl = __half2float(__ushort_as_half((unsigned short)(b & 0xffffu)));
  float bh = __half2float(__ushort_as_half((unsigned short)(b >> 16)));
  return fmaf(ah, bh, fmaf(al, bl, c));
#endif
}

__device__ __forceinline__ unsigned pack2f(float a, float b) {
  return (unsigned)__half_as_ushort(__float2half(a)) |
         ((unsigned)__half_as_ushort(__float2half(b)) << 16);
}

__device__ __forceinline__ float fast_sig(float x) {
  float e = __builtin_amdgcn_exp2f(x * -1.442695040888963f);
  return __builtin_amdgcn_rcpf(1.f + e);
}
__device__ __forceinline__ float fast_tanh(float x) {
  float e = __builtin_amdgcn_exp2f(x * -2.885390081777926f);
  return fmaf(2.f, __builtin_amdgcn_rcpf(1.f + e), -1.f);
}

__device__ __forceinline__ f32x4v mfma16(uint4 a, uint4 b, f32x4v c) {
  return __builtin_amdgcn_mfma_f32_16x16x32_f16(
      __builtin_bit_cast(f16x8, a), __builtin_bit_cast(f16x8, b), c, 0, 0, 0);
}

// ---------------- prep ----------------
__global__ void prep(const float* __restrict__ dWih, const float* __restrict__ dWhh,
                     const float* __restrict__ dbih, const float* __restrict__ dbhh,
                     const float* __restrict__ eWih, const float* __restrict__ eWhh,
                     const float* __restrict__ ebih, const float* __restrict__ ebhh,
                     const float* __restrict__ fcW,  const float* __restrict__ fcb,
                     char* __restrict__ wsb)
{
  int idx = blockIdx.x * 256 + threadIdx.x;
  if (idx < 25600) {                       // packed weight rows (pairs)
    int q = idx >> 9, t = idx & 511;
    unsigned w2p = 0, wdp = 0, wep = 0;
    if (t < 400) {
      int r = (t & 3) * 100 + (t >> 2);
      int j0 = 2 * q, j1 = 2 * q + 1;
      float wd0 = dWhh[r * 100 + j0], wd1 = dWhh[r * 100 + j1];
      float we0 = eWhh[r * 100 + j0], we1 = eWhh[r * 100 + j1];
      float s0 = 0.f, s1 = 0.f;
      for (int f = 0; f < 150; ++f) {
        float a = dWih[r * 150 + f];
        s0 = fmaf(a, fcW[f * 100 + j0], s0);
        s1 = fmaf(a, fcW[f * 100 + j1], s1);
      }
      w2p = pack2f(wd0 + s0, wd1 + s1);
      wdp = pack2f(wd0, wd1);
      wep = pack2f(we0, we1);
    }
    ((unsigned*)(wsb + B_W2P))[idx] = w2p;
    ((unsigned*)(wsb + B_WDP))[idx] = wdp;
    ((unsigned*)(wsb + B_WEP))[idx] = wep;
  } else if (idx < 25600 + 38400) {        // packed f16 enc_Wih
    int k = idx - 25600; int d = k >> 9, t = k & 511;
    unsigned pk = 0;
    if (t < 400) {
      int r = (t & 3) * 100 + (t >> 2);
      pk = pack2f(eWih[r * 150 + 2 * d], eWih[r * 150 + 2 * d + 1]);
    }
    ((unsigned*)(wsb + B_PIH))[k] = pk;
  } else if (idx < 25600 + 38400 + 512) {  // biases
    int t = idx - (25600 + 38400);
    float be = 0.f, b1 = 0.f, bf = 0.f;
    if (t < 400) {
      int r = (t & 3) * 100 + (t >> 2);
      be = ebih[r] + ebhh[r];
      b1 = dbih[r] + dbhh[r];
      float acc = 0.f;
      for (int f = 0; f < 150; ++f) acc = fmaf(dWih[r * 150 + f], fcb[f], acc);
      bf = b1 + acc;
    }
    ((float*)(wsb + B_BENC))[t] = be;
    ((float*)(wsb + B_B1))[t]   = b1;
    ((float*)(wsb + B_BEFF))[t] = bf;
  }
}

// ---------------- recurrent: fused-K MFMA, one dispatch, 599 steps ----------------
// 32 blocks x 16 samples, 7 waves. Wave w owns M-tiles {w+7i}; lane(sp=lane&15,q=lane>>4).
// Encoder: K=256 fused [h|x_t|pad], 8 K-steps; x_t staged f32->f16 per step (dbuf).
// Decoder: K=128 (h|pad), 4 K-steps, zero-padded A beyond pair 50.
// D-frag lane-local: acc = (i,f,g,o) of cell 4*tile+q, sample sp -> no shuffles.
__global__ __launch_bounds__(448, 2)
void recurrent(const float* __restrict__ x, char* __restrict__ wsb)
{
  const int tid  = threadIdx.x;
  const int w    = tid >> 6;
  const int lane = tid & 63;
  const int sp   = lane & 15;
  const int q    = lane >> 4;
  const int nb   = blockIdx.x * 16;

  __shared__ unsigned short hx[2][16][264];  // [buf][sample][K(256)+pad], f16
  for (int k = tid; k < 2 * 16 * 264; k += 448) ((unsigned short*)hx)[k] = 0;

  const unsigned* WEP = (const unsigned*)(wsb + B_WEP);
  const unsigned* WDP = (const unsigned*)(wsb + B_WDP);
  const unsigned* W2P = (const unsigned*)(wsb + B_W2P);
  const unsigned* PIH = (const unsigned*)(wsb + B_PIH);

  const int nt = (w < 4) ? 4 : 3;           // tiles this wave owns (25 total)
  int cells[4];
  float4 bs[4];
  uint4 af[4][8];
#pragma unroll
  for (int i = 0; i < 4; ++i) {
    const int tile = (i < nt) ? (w + 7 * i) : 0;
    const int col = tile * 16 + sp;
    cells[i] = 4 * tile + q;
#pragma unroll
    for (int kk = 0; kk < 8; ++kk) {
      unsigned e[4];
#pragma unroll
      for (int l = 0; l < 4; ++l) {
        const int p = kk * 16 + q * 4 + l;   // fused K-pair index
        unsigned v = 0u;
        if (p < 50) v = WEP[p * 512 + col];
        else if (p < 125) v = PIH[(p - 50) * 512 + col];
        e[l] = v;
      }
      af[i][kk] = make_uint4(e[0], e[1], e[2], e[3]);
    }
    bs[i] = ((const float4*)(wsb + B_BENC))[cells[i]];
  }

  // x staging map: threads 0..399 -> (sample ssp, 6 features starting at 6*sr)
  const bool stg = tid < 400;
  const int ssp = tid / 25;
  const int sr  = tid - ssp * 25;
  const float* xb = x + (size_t)(nb + (stg ? ssp : 0)) * 45000;
  int soff[6];
#pragma unroll
  for (int l = 0; l < 6; ++l) {
    const int f = sr * 6 + l;
    const int cd = f / 50;
    soff[l] = cd * 15000 + (f - cd * 50);
  }
  const int sdst = (stg ? ssp : 0) * 264 + 100 + sr * 6;  // ushort idx in buffer

  unsigned short* histn = (unsigned short*)(wsb + B_HIST) + (size_t)(nb + sp) * HIST_STRIDE;

  // prologue: zeros visible, then stage x(0) into buf0
  __syncthreads();
  if (stg) {
    float xv[6];
#pragma unroll
    for (int l = 0; l < 6; ++l) xv[l] = xb[soff[l]];
    unsigned short* d = &hx[0][0][0] + sdst;
    *(unsigned*)(d + 0) = pack2f(xv[0], xv[1]);
    *(unsigned*)(d + 2) = pack2f(xv[2], xv[3]);
    *(unsigned*)(d + 4) = pack2f(xv[4], xv[5]);
  }
  __syncthreads();

  float cst[4] = {0.f, 0.f, 0.f, 0.f};

  // ---- encoder: 300 steps, K=256 ----
  for (int t = 0; t < 300; ++t) {
    const int rd = t & 1, wr = rd ^ 1;
    const bool pf = stg && (t < 299);
    float xv[6];
    if (pf) {
      const int to = (t + 1) * 50;
#pragma unroll
      for (int l = 0; l < 6; ++l) xv[l] = xb[soff[l] + to];
    }
    f32x4v acc[4];
#pragma unroll
    for (int i = 0; i < 4; ++i) {
      acc[i][0] = bs[i].x; acc[i][1] = bs[i].y;
      acc[i][2] = bs[i].z; acc[i][3] = bs[i].w;
    }
#pragma unroll
    for (int kk = 0; kk < 8; ++kk) {
      uint4 b = *(const uint4*)(&hx[rd][sp][kk * 32 + q * 8]);
#pragma unroll
      for (int i = 0; i < 4; ++i)
        if (i < nt) acc[i] = mfma16(af[i][kk], b, acc[i]);
    }
#pragma unroll
    for (int i = 0; i < 4; ++i) {
      if (i < nt) {
        float ii = fast_sig(acc[i][0]), ff = fast_sig(acc[i][1]);
        float gg = fast_tanh(acc[i][2]), oo = fast_sig(acc[i][3]);
        cst[i] = fmaf(ff, cst[i], ii * gg);
        float h = oo * fast_tanh(cst[i]);
        hx[wr][sp][cells[i]] = __half_as_ushort(__float2half(h));
      }
    }
    if (pf) {
      unsigned short* d = &hx[wr][0][0] + sdst;
      *(unsigned*)(d + 0) = pack2f(xv[0], xv[1]);
      *(unsigned*)(d + 2) = pack2f(xv[2], xv[3]);
      *(unsigned*)(d + 4) = pack2f(xv[4], xv[5]);
    }
    __syncthreads();
  }

  // ---- decoder A-frag reload helper (K=128, zero beyond pair 50) ----
  auto loadA4 = [&](const unsigned* W, unsigned bofs) {
#pragma unroll
    for (int i = 0; i < 4; ++i) {
      const int tile = (i < nt) ? (w + 7 * i) : 0;
      const int col = tile * 16 + sp;
#pragma unroll
      for (int kk = 0; kk < 4; ++kk) {
        unsigned e[4];
#pragma unroll
        for (int l = 0; l < 4; ++l) {
          const int p = kk * 16 + q * 4 + l;
          e[l] = (p < 50) ? W[p * 512 + col] : 0u;
        }
        af[i][kk] = make_uint4(e[0], e[1], e[2], e[3]);
      }
      bs[i] = ((const float4*)(wsb + bofs))[cells[i]];
    }
  };

  // decoder step 1: plain Whh (input zeros); enc final h is in hx[0]
  loadA4(WDP, B_B1);
  {
    f32x4v acc[4];
#pragma unroll
    for (int i = 0; i < 4; ++i) {
      acc[i][0] = bs[i].x; acc[i][1] = bs[i].y;
      acc[i][2] = bs[i].z; acc[i][3] = bs[i].w;
    }
#pragma unroll
    for (int kk = 0; kk < 4; ++kk) {
      uint4 b = *(const uint4*)(&hx[0][sp][kk * 32 + q * 8]);
#pragma unroll
      for (int i = 0; i < 4; ++i)
        if (i < nt) acc[i] = mfma16(af[i][kk], b, acc[i]);
    }
#pragma unroll
    for (int i = 0; i < 4; ++i) {
      if (i < nt) {
        float ii = fast_sig(acc[i][0]), ff = fast_sig(acc[i][1]);
        float gg = fast_tanh(acc[i][2]), oo = fast_sig(acc[i][3]);
        cst[i] = fmaf(ff, cst[i], ii * gg);
        float h = oo * fast_tanh(cst[i]);
        hx[1][sp][cells[i]] = __half_as_ushort(__float2half(h));
        histn[cells[i]] = __half_as_ushort(__float2half(h));
      }
    }
    __syncthreads();
  }
  // decoder steps 2..299: folded W2
  loadA4(W2P, B_BEFF);
  for (int s = 2; s <= 299; ++s) {
    const int rd = (299 + s) & 1, wr = rd ^ 1;
    f32x4v acc[4];
#pragma unroll
    for (int i = 0; i < 4; ++i) {
      acc[i][0] = bs[i].x; acc[i][1] = bs[i].y;
      acc[i][2] = bs[i].z; acc[i][3] = bs[i].w;
    }
#pragma unroll
    for (int kk = 0; kk < 4; ++kk) {
      uint4 b = *(const uint4*)(&hx[rd][sp][kk * 32 + q * 8]);
#pragma unroll
      for (int i = 0; i < 4; ++i)
        if (i < nt) acc[i] = mfma16(af[i][kk], b, acc[i]);
    }
#pragma unroll
    for (int i = 0; i < 4; ++i) {
      if (i < nt) {
        float ii = fast_sig(acc[i][0]), ff = fast_sig(acc[i][1]);
        float gg = fast_tanh(acc[i][2]), oo = fast_sig(acc[i][3]);
        cst[i] = fmaf(ff, cst[i], ii * gg);
        float h = oo * fast_tanh(cst[i]);
        hx[wr][sp][cells[i]] = __half_as_ushort(__float2half(h));
        histn[(s - 1) * 100 + cells[i]] = __half_as_ushort(__float2half(h));
      }
    }
    __syncthreads();
  }
}

// ---------------- emit: out[n][t] = fcW @ h_{t-1} + fcb ----------------
__global__ __launch_bounds__(192, 4)
void emit(const char* __restrict__ wsb, const float* __restrict__ fcW,
          const float* __restrict__ fcb, float* __restrict__ out)
{
  const int f = threadIdx.x;
  const int n = blockIdx.x;
  const int z = blockIdx.y;
  __shared__ unsigned short hl[15008];

  const uint4* src = (const uint4*)((const unsigned short*)(wsb + B_HIST) +
                                    (size_t)n * HIST_STRIDE + z * 15000);
  for (int k = f; k < 1875; k += 192) ((uint4*)hl)[k] = src[k];

  const bool on = f < 150;
  unsigned fw[50];
  float bias = 0.f;
  if (on) {
    const float* fp = fcW + f * 100;
#pragma unroll
    for (int q = 0; q < 50; ++q) fw[q] = pack2f(fp[2 * q], fp[2 * q + 1]);
    bias = fcb[f];
  }
  __syncthreads();

  if (!on) return;
  const int cc = f / 50, r = f - cc * 50;
  float* ob = out + (size_t)n * 45000 + cc * 15000 + r;
  if (z == 0) ob[0] = 0.f;
  const int rows = z ? 149 : 150;
  for (int tl = 0; tl < rows; ++tl) {
    const uint4* row = (const uint4*)(hl + tl * 100);
    float a0 = bias, a1 = 0.f, a2 = 0.f, a3 = 0.f;
#pragma unroll
    for (int ch = 0; ch < 12; ++ch) {
      uint4 v = row[ch];
      a0 = fdot2u(fw[4 * ch + 0], v.x, a0);
      a1 = fdot2u(fw[4 * ch + 1], v.y, a1);
      a2 = fdot2u(fw[4 * ch + 2], v.z, a2);
      a3 = fdot2u(fw[4 * ch + 3], v.w, a3);
    }
    uint2 v2 = *(const uint2*)(hl + tl * 100 + 96);
    a0 = fdot2u(fw[48], v2.x, a0);
    a1 = fdot2u(fw[49], v2.y, a1);
    const int tt = z * 150 + tl + 1;
    ob[tt * 50] = (a0 + a1) + (a2 + a3);
  }
}

extern "C" void kernel_launch(void* const* d_in, const int* in_sizes, int n_in,
                              void* d_out, int out_size, void* d_ws, size_t ws_size,
                              hipStream_t stream) {
  const float* x    = (const float*)d_in[0];
  const float* eWih = (const float*)d_in[1];
  const float* eWhh = (const float*)d_in[2];
  const float* ebih = (const float*)d_in[3];
  const float* ebhh = (const float*)d_in[4];
  const float* dWih = (const float*)d_in[5];
  const float* dWhh = (const float*)d_in[6];
  const float* dbih = (const float*)d_in[7];
  const float* dbhh = (const float*)d_in[8];
  const float* fcW  = (const float*)d_in[9];
  const float* fcb  = (const float*)d_in[10];
  float* out = (float*)d_out;
  char* wsb  = (char*)d_ws;

  prep<<<252, 256, 0, stream>>>(dWih, dWhh, dbih, dbhh, eWih, eWhh, ebih, ebhh, fcW, fcb, wsb);
  // fused-K recurrence: no pre, no xg, no phase split — one 599-step dispatch
  recurrent<<<32, 448, 0, stream>>>(x, wsb);
  emit<<<dim3(512, 2), 192, 0, stream>>>(wsb, fcW, fcb, out);
}